// Round 5
// baseline (118.916 us; speedup 1.0000x reference)
//
#include <hip/hip_runtime.h>
#include <hip/hip_bf16.h>
#include <hip/hip_fp16.h>

typedef unsigned short ushort_t;
typedef unsigned int uint_t;

#define HH 128
#define WW 128
#define CIN 128
#define COUT 128
#define NPIX (HH * WW)          // 16384 pixels per batch
#define PIXB 256                // bytes per bf16 pixel (128 ch * 2B)
#define BP 32                   // positions per block
#define LDB 136                 // B row stride elems (128 + 8 pad)
#define ASZ 4096                // A buffer elems per tap (64 o x 64 c, swizzled)
#define BSZ (BP * LDB)          // 4352
#define NTASK (9 * BP)          // 288

typedef __attribute__((ext_vector_type(8))) short bf16x8;
typedef __attribute__((ext_vector_type(4))) float f32x4;

static __device__ __forceinline__ ushort_t f2bf(float f) {
  union { float f; uint_t u; } x; x.f = f;
  uint_t u = x.u;
  return (ushort_t)((u + 0x7FFFu + ((u >> 16) & 1u)) >> 16);
}
static __device__ __forceinline__ float bflo2f(uint_t u) {
  union { uint_t u; float f; } x; x.u = u << 16; return x.f;
}
static __device__ __forceinline__ float bfhi2f(uint_t u) {
  union { uint_t u; float f; } x; x.u = u & 0xFFFF0000u; return x.f;
}
static __device__ __forceinline__ float h2f(ushort_t us) {
  union { ushort_t u; __half h; } x; x.u = us; return __half2float(x.h);
}
static __device__ __forceinline__ int imin(int a, int b) { return a < b ? a : b; }
static __device__ __forceinline__ int imax(int a, int b) { return a > b ? a : b; }

// K0: weight prep (first 144 blocks) + offset passthrough copy (rest).
// weight (64,64,3,3) -> bf16, tap-major, XOR-swizzled granules:
// dest elem for (k,o,c): k*4096 + (((o*8 + (c>>3)) ^ (o&7)) * 8 + (c&7))
__global__ void prep_misc(const float* __restrict__ w, ushort_t* __restrict__ wbf,
                          const float4* __restrict__ off_in, float4* __restrict__ off_out,
                          int n4) {
  int bx = blockIdx.x;
  if (bx < 144) {
    int i = bx * 256 + threadIdx.x;
    int k = i >> 12, e = i & 4095;
    int gp = e >> 3, sub = e & 7;
    int o = gp >> 3;
    int c = (((gp & 7) ^ (o & 7)) << 3) | sub;
    wbf[i] = f2bf(w[(o * 64 + c) * 9 + k]);
  } else {
    int i = (bx - 144) * 256 + threadIdx.x;
    if (i < n4) off_out[i] = off_in[i];
  }
}

// K1: x BCHW f32 -> NHWC bf16
__global__ void transpose_nchw_nhwc(const float* __restrict__ in, uint_t* __restrict__ out) {
  __shared__ float tile[32][33];
  int b = blockIdx.z;
  int c0 = blockIdx.y * 32;
  int s0 = blockIdx.x * 32;
  int tx = threadIdx.x;   // 0..31
  int ty = threadIdx.y;   // 0..7
  const float* inb = in + (size_t)b * CIN * NPIX;
  uint_t* outb = out + (size_t)b * NPIX * (CIN / 2);
#pragma unroll
  for (int i = 0; i < 4; ++i) {
    int c = c0 + ty + 8 * i;
    tile[ty + 8 * i][tx] = inb[(size_t)c * NPIX + s0 + tx];
  }
  __syncthreads();
  int idx = ty * 32 + tx;
  int u = idx & 15;
  int sl = idx >> 4;
#pragma unroll
  for (int i = 0; i < 2; ++i) {
    int s = sl + 16 * i;
    __hip_bfloat162 pk = __float22bfloat162_rn(
        make_float2(tile[2 * u][s], tile[2 * u + 1][s]));
    outb[(size_t)(s0 + s) * (CIN / 2) + (c0 >> 1) + u] = *(uint_t*)&pk;
  }
}

// bilinear commit helper: 4 corner uint4s (8 bf16 ch each) + packed f16 weights
static __device__ __forceinline__ void commit_bilinear(
    const uint4* cf, uint2 wz, ushort_t* dst) {
  float w00 = h2f((ushort_t)wz.x), w01 = h2f((ushort_t)(wz.x >> 16));
  float w10 = h2f((ushort_t)wz.y), w11 = h2f((ushort_t)(wz.y >> 16));
  float va[8];
#pragma unroll
  for (int j = 0; j < 4; ++j) {
    uint_t u0 = ((const uint_t*)&cf[0])[j], u1 = ((const uint_t*)&cf[1])[j];
    uint_t u2 = ((const uint_t*)&cf[2])[j], u3 = ((const uint_t*)&cf[3])[j];
    va[2*j]   = w00*bflo2f(u0) + w01*bflo2f(u1) + w10*bflo2f(u2) + w11*bflo2f(u3);
    va[2*j+1] = w00*bfhi2f(u0) + w01*bfhi2f(u1) + w10*bfhi2f(u2) + w11*bfhi2f(u3);
  }
  union { __hip_bfloat162 h2v[4]; uint4 u4; } pk;
#pragma unroll
  for (int j = 0; j < 4; ++j)
    pk.h2v[j] = __float22bfloat162_rn(make_float2(va[2*j], va[2*j+1]));
  *(uint4*)dst = pk.u4;
}

// K3: fused gather + MFMA. 2048 blocks x 512 thr. Tile: 128 o x 32 pos, 9 taps.
// 2-tap-deep gather pipeline; raw barriers with counted vmcnt (A-gload drain only).
__global__ __launch_bounds__(512, 8)
void deform_main(const ushort_t* __restrict__ xtb, const float* __restrict__ off,
                 const ushort_t* __restrict__ wbf, const float* __restrict__ bias,
                 float* __restrict__ out) {
  __shared__ __align__(16) ushort_t Alds[2 * ASZ];   // weight, swizzled granules
  __shared__ __align__(16) ushort_t Blds[2 * BSZ];   // val [p][c]
  __shared__ __align__(16) uint4 meta[NTASK];        // u16 idx x4 | f16 w x4

  const int n  = blockIdx.x;
  const int l  = (n & 7) * 256 + (n >> 3);           // XCD swizzle (2048%8==0)
  const int b  = l >> 9;
  const int rr = l & 511;
  const int ho = rr >> 2;
  const int wo0 = (rr & 3) << 5;

  const int tid  = threadIdx.x;
  const int wv   = tid >> 6;
  const int lane = tid & 63;
  const int r    = lane & 15;
  const int g    = lane >> 4;
  const int ob   = (wv & 3) << 5;
  const int pb   = (wv >> 2) << 4;
  const int arow = ob & 32;
  const int cb   = ob & 64;

  // ---- meta: 9 taps x 32 positions, compact 16B/task ----
  if (tid < NTASK) {
    int k = tid >> 5, p = tid & 31;
    int ky = k / 3, kx = k % 3;
    int wo = wo0 + p;
    float dy = off[((b * 18 + 2 * k) * HH + ho) * WW + wo];
    float dx = off[((b * 18 + 2 * k + 1) * HH + ho) * WW + wo];
    float py = dy + (float)(ky + ho - 1);
    float px = dx + (float)(kx + wo - 1);
    float y0f = floorf(py), x0f = floorf(px);
    float ly = py - y0f, lx = px - x0f;
    int y0 = (int)y0f, x0 = (int)x0f;
    int y1 = y0 + 1, x1 = x0 + 1;
    float wy0 = 1.f - ly, wx0 = 1.f - lx;
    bool vy0 = (y0 >= 0) & (y0 < HH), vy1 = (y1 >= 0) & (y1 < HH);
    bool vx0 = (x0 >= 0) & (x0 < WW), vx1 = (x1 >= 0) & (x1 < WW);
    int y0c = imin(imax(y0, 0), HH - 1), y1c = imin(imax(y1, 0), HH - 1);
    int x0c = imin(imax(x0, 0), WW - 1), x1c = imin(imax(x1, 0), WW - 1);
    uint_t i00 = y0c * WW + x0c, i01 = y0c * WW + x1c;
    uint_t i10 = y1c * WW + x0c, i11 = y1c * WW + x1c;
    float f00 = (vy0 && vx0) ? wy0 * wx0 : 0.f;
    float f01 = (vy0 && vx1) ? wy0 * lx  : 0.f;
    float f10 = (vy1 && vx0) ? ly  * wx0 : 0.f;
    float f11 = (vy1 && vx1) ? ly  * lx  : 0.f;
    union { __half h; ushort_t u; } h00, h01, h10, h11;
    h00.h = __float2half_rn(f00); h01.h = __float2half_rn(f01);
    h10.h = __float2half_rn(f10); h11.h = __float2half_rn(f11);
    uint4 m;
    m.x = i00 | (i01 << 16);
    m.y = i10 | (i11 << 16);
    m.z = (uint_t)h00.u | ((uint_t)h01.u << 16);
    m.w = (uint_t)h10.u | ((uint_t)h11.u << 16);
    meta[tid] = m;
  }

  // gather mapping: one task (4 corners, 8 ch) per thread per tap
  const int q  = tid & 15;            // channel octet
  const int p0 = tid >> 4;            // position 0..31
  const char* xb = (const char*)xtb + (size_t)b * NPIX * PIXB + q * 16;

  // A gload mapping: thread copies 16B; pre-swizzled source is linear
  const char* asrc = (const char*)wbf + tid * 16;
  char* adst0 = (char*)Alds + wv * 1024;

  uint4 cf[2][4];     // 2-deep in-flight gather sets
  uint2 wr[2];        // corner weights (packed f16) per set

  __syncthreads();  // meta ready (full drain once is fine)

  // ---- prologue ----
  __builtin_amdgcn_sched_barrier(0);
  __builtin_amdgcn_global_load_lds(
      (const __attribute__((address_space(1))) uint_t*)asrc,
      (__attribute__((address_space(3))) uint_t*)adst0, 16, 0, 0);
  __builtin_amdgcn_sched_barrier(0);
  {
    uint4 m = meta[p0];
    cf[0][0] = *(const uint4*)(xb + ((m.x & 0xFFFFu) << 8));
    cf[0][1] = *(const uint4*)(xb + ((m.x >> 16) << 8));
    cf[0][2] = *(const uint4*)(xb + ((m.y & 0xFFFFu) << 8));
    cf[0][3] = *(const uint4*)(xb + ((m.y >> 16) << 8));
    wr[0] = make_uint2(m.z, m.w);
  }
  __builtin_amdgcn_sched_barrier(0);
  {
    uint4 m = meta[32 + p0];
    cf[1][0] = *(const uint4*)(xb + ((m.x & 0xFFFFu) << 8));
    cf[1][1] = *(const uint4*)(xb + ((m.x >> 16) << 8));
    cf[1][2] = *(const uint4*)(xb + ((m.y & 0xFFFFu) << 8));
    cf[1][3] = *(const uint4*)(xb + ((m.y >> 16) << 8));
    wr[1] = make_uint2(m.z, m.w);
  }
  __builtin_amdgcn_sched_barrier(0);
  commit_bilinear(cf[0], wr[0], &Blds[p0 * LDB + q * 8]);   // compiler waits g[0] regs
  asm volatile("s_waitcnt lgkmcnt(0)" ::: "memory");
  asm volatile("s_waitcnt vmcnt(4)" ::: "memory");          // A[0] done; g[1] in flight
  __builtin_amdgcn_sched_barrier(0);
  __builtin_amdgcn_s_barrier();

  f32x4 acc0 = {0.f, 0.f, 0.f, 0.f};
  f32x4 acc1 = {0.f, 0.f, 0.f, 0.f};

  const int o0r = arow + r, o1r = arow + 16 + r;
  const int g0base = (o0r << 3) + g, g0m = o0r & 7;
  const int g1base = (o1r << 3) + g, g1m = o1r & 7;

  // ---- main loop: 9 taps, fully unrolled, 2-deep gather pipeline ----
#pragma unroll
  for (int t = 0; t < 9; ++t) {
    const int bs = t & 1;

    __builtin_amdgcn_sched_barrier(0);
    if (t < 8) {
      __builtin_amdgcn_global_load_lds(
          (const __attribute__((address_space(1))) uint_t*)(asrc + (t + 1) * 8192),
          (__attribute__((address_space(3))) uint_t*)(adst0 + ((t + 1) & 1) * 8192),
          16, 0, 0);
    }
    __builtin_amdgcn_sched_barrier(0);
    if (t < 7) {
      const int n2 = t & 1;            // (t+2)&1
      uint4 m = meta[(t + 2) * 32 + p0];
      cf[n2][0] = *(const uint4*)(xb + ((m.x & 0xFFFFu) << 8));
      cf[n2][1] = *(const uint4*)(xb + ((m.x >> 16) << 8));
      cf[n2][2] = *(const uint4*)(xb + ((m.y & 0xFFFFu) << 8));
      cf[n2][3] = *(const uint4*)(xb + ((m.y >> 16) << 8));
      wr[n2] = make_uint2(m.z, m.w);
    }
    __builtin_amdgcn_sched_barrier(0);

    // GEMM on current buffer: K=64, 2 steps of 32
    {
      const ushort_t* Ab = &Alds[bs * ASZ];
      const ushort_t* Bb = &Blds[bs * BSZ];
#pragma unroll
      for (int ks = 0; ks < 2; ++ks) {
        int kk = ks * 32 + g * 8;
        bf16x8 a0 = *(const bf16x8*)&Ab[(((g0base + (ks << 2)) ^ g0m) << 3)];
        bf16x8 a1 = *(const bf16x8*)&Ab[(((g1base + (ks << 2)) ^ g1m) << 3)];
        bf16x8 bbf = *(const bf16x8*)&Bb[(pb + r) * LDB + cb + kk];
        acc0 = __builtin_amdgcn_mfma_f32_16x16x32_bf16(a0, bbf, acc0, 0, 0, 0);
        acc1 = __builtin_amdgcn_mfma_f32_16x16x32_bf16(a1, bbf, acc1, 0, 0, 0);
      }
    }

    // commit tap t+1 into the other buffer (gathers issued 2 phases ago)
    if (t < 8) {
      const int nc = (t + 1) & 1;
      commit_bilinear(cf[nc], wr[nc], &Blds[nc * BSZ + p0 * LDB + q * 8]);
    }

    if (t < 8) {
      asm volatile("s_waitcnt lgkmcnt(0)" ::: "memory");
      if (t < 7) {
        asm volatile("s_waitcnt vmcnt(4)" ::: "memory");  // A[t+1] done; g[t+2] fly
      } else {
        asm volatile("s_waitcnt vmcnt(0)" ::: "memory");  // A[8] done (no gathers)
      }
      __builtin_amdgcn_sched_barrier(0);
      __builtin_amdgcn_s_barrier();
    }
  }

  // ---- epilogue ----
  int wo = wo0 + pb + r;
#pragma unroll
  for (int qq = 0; qq < 4; ++qq) {
    int o0 = ob + 4 * g + qq;
    int o1 = o0 + 16;
    out[((size_t)(b * COUT + o0) * HH + ho) * WW + wo] = acc0[qq] + bias[o0 & 63];
    out[((size_t)(b * COUT + o1) * HH + ho) * WW + wo] = acc1[qq] + bias[o1 & 63];
  }
}

extern "C" void kernel_launch(void* const* d_in, const int* in_sizes, int n_in,
                              void* d_out, int out_size, void* d_ws, size_t ws_size,
                              hipStream_t stream) {
  const float* x      = (const float*)d_in[0];
  const float* offset = (const float*)d_in[1];
  const float* weight = (const float*)d_in[2];
  const float* bias   = (const float*)d_in[3];
  float* out = (float*)d_out;

  const size_t xt_elems = (size_t)4 * NPIX * CIN;           // 8,388,608 bf16
  ushort_t* xtb = (ushort_t*)d_ws;
  ushort_t* wbf = (ushort_t*)((char*)d_ws + xt_elems * sizeof(ushort_t));

  const int off_elems = 4 * 18 * NPIX;
  const int n4 = off_elems / 4;                             // 294912 float4s
  prep_misc<<<144 + (n4 + 255) / 256, 256, 0, stream>>>(
      weight, wbf, (const float4*)offset,
      (float4*)(out + (size_t)4 * COUT * NPIX), n4);

  transpose_nchw_nhwc<<<dim3(512, 4, 4), dim3(32, 8), 0, stream>>>(x, (uint_t*)xtb);

  deform_main<<<2048, 512, 0, stream>>>(xtb, offset, wbf, bias, out);
}

// Round 6
// 60.935 us; speedup vs baseline: 1.9515x; 1.9515x over previous
//
#include <hip/hip_runtime.h>
#include <hip/hip_bf16.h>
#include <hip/hip_fp16.h>

typedef unsigned short ushort_t;
typedef unsigned int uint_t;

#define HH 128
#define WW 128
#define CIN 128
#define COUT 128
#define NPIX (HH * WW)          // 16384 pixels per batch
#define PIXB 256                // bytes per bf16 pixel (128 ch * 2B)
#define BP 32                   // positions per block
#define LDB 136                 // B row stride elems (128 + 8 pad)
#define ASZ 4096                // A buffer elems per tap (64 o x 64 c, swizzled)
#define BSZ (BP * LDB)          // 4352
#define NTASK (9 * BP)          // 288

typedef __attribute__((ext_vector_type(8))) short bf16x8;
typedef __attribute__((ext_vector_type(4))) float f32x4;

static __device__ __forceinline__ ushort_t f2bf(float f) {
  union { float f; uint_t u; } x; x.f = f;
  uint_t u = x.u;
  return (ushort_t)((u + 0x7FFFu + ((u >> 16) & 1u)) >> 16);
}
static __device__ __forceinline__ float bflo2f(uint_t u) {
  union { uint_t u; float f; } x; x.u = u << 16; return x.f;
}
static __device__ __forceinline__ float bfhi2f(uint_t u) {
  union { uint_t u; float f; } x; x.u = u & 0xFFFF0000u; return x.f;
}
static __device__ __forceinline__ float h2f(ushort_t us) {
  union { ushort_t u; __half h; } x; x.u = us; return __half2float(x.h);
}
static __device__ __forceinline__ int imin(int a, int b) { return a < b ? a : b; }
static __device__ __forceinline__ int imax(int a, int b) { return a > b ? a : b; }

// K0: weight prep (first 144 blocks) + offset passthrough copy (rest).
// weight (64,64,3,3) -> bf16, tap-major, XOR-swizzled granules:
// dest elem for (k,o,c): k*4096 + (((o*8 + (c>>3)) ^ (o&7)) * 8 + (c&7))
__global__ void prep_misc(const float* __restrict__ w, ushort_t* __restrict__ wbf,
                          const float4* __restrict__ off_in, float4* __restrict__ off_out,
                          int n4) {
  int bx = blockIdx.x;
  if (bx < 144) {
    int i = bx * 256 + threadIdx.x;
    int k = i >> 12, e = i & 4095;
    int gp = e >> 3, sub = e & 7;
    int o = gp >> 3;
    int c = (((gp & 7) ^ (o & 7)) << 3) | sub;
    wbf[i] = f2bf(w[(o * 64 + c) * 9 + k]);
  } else {
    int i = (bx - 144) * 256 + threadIdx.x;
    if (i < n4) off_out[i] = off_in[i];
  }
}

// K1: x BCHW f32 -> NHWC bf16
__global__ void transpose_nchw_nhwc(const float* __restrict__ in, uint_t* __restrict__ out) {
  __shared__ float tile[32][33];
  int b = blockIdx.z;
  int c0 = blockIdx.y * 32;
  int s0 = blockIdx.x * 32;
  int tx = threadIdx.x;   // 0..31
  int ty = threadIdx.y;   // 0..7
  const float* inb = in + (size_t)b * CIN * NPIX;
  uint_t* outb = out + (size_t)b * NPIX * (CIN / 2);
#pragma unroll
  for (int i = 0; i < 4; ++i) {
    int c = c0 + ty + 8 * i;
    tile[ty + 8 * i][tx] = inb[(size_t)c * NPIX + s0 + tx];
  }
  __syncthreads();
  int idx = ty * 32 + tx;
  int u = idx & 15;
  int sl = idx >> 4;
#pragma unroll
  for (int i = 0; i < 2; ++i) {
    int s = sl + 16 * i;
    __hip_bfloat162 pk = __float22bfloat162_rn(
        make_float2(tile[2 * u][s], tile[2 * u + 1][s]));
    outb[(size_t)(s0 + s) * (CIN / 2) + (c0 >> 1) + u] = *(uint_t*)&pk;
  }
}

// bilinear commit helper: 4 corner uint4s (8 bf16 ch each) + packed f16 weights
static __device__ __forceinline__ void commit_bilinear(
    const uint4* cf, uint2 wz, ushort_t* dst) {
  float w00 = h2f((ushort_t)wz.x), w01 = h2f((ushort_t)(wz.x >> 16));
  float w10 = h2f((ushort_t)wz.y), w11 = h2f((ushort_t)(wz.y >> 16));
  float va[8];
#pragma unroll
  for (int j = 0; j < 4; ++j) {
    uint_t u0 = ((const uint_t*)&cf[0])[j], u1 = ((const uint_t*)&cf[1])[j];
    uint_t u2 = ((const uint_t*)&cf[2])[j], u3 = ((const uint_t*)&cf[3])[j];
    va[2*j]   = w00*bflo2f(u0) + w01*bflo2f(u1) + w10*bflo2f(u2) + w11*bflo2f(u3);
    va[2*j+1] = w00*bfhi2f(u0) + w01*bfhi2f(u1) + w10*bfhi2f(u2) + w11*bfhi2f(u3);
  }
  union { __hip_bfloat162 h2v[4]; uint4 u4; } pk;
#pragma unroll
  for (int j = 0; j < 4; ++j)
    pk.h2v[j] = __float22bfloat162_rn(make_float2(va[2*j], va[2*j+1]));
  *(uint4*)dst = pk.u4;
}

// K3: fused gather + MFMA. 2048 blocks x 512 thr. Tile: 128 o x 32 pos, 9 taps.
// 2-tap-deep gather pipeline; raw barriers with counted vmcnt (A-gload drain only).
// launch_bounds (512,4): 128 VGPR/wave -- the 2-deep in-flight payload (~100 VGPR)
// MUST fit in registers; (512,8)=64 VGPR spilled to scratch (R4: +280MB HBM traffic).
__global__ __launch_bounds__(512, 4)
void deform_main(const ushort_t* __restrict__ xtb, const float* __restrict__ off,
                 const ushort_t* __restrict__ wbf, const float* __restrict__ bias,
                 float* __restrict__ out) {
  __shared__ __align__(16) ushort_t Alds[2 * ASZ];   // weight, swizzled granules
  __shared__ __align__(16) ushort_t Blds[2 * BSZ];   // val [p][c]
  __shared__ __align__(16) uint4 meta[NTASK];        // u16 idx x4 | f16 w x4

  const int n  = blockIdx.x;
  const int l  = (n & 7) * 256 + (n >> 3);           // XCD swizzle (2048%8==0)
  const int b  = l >> 9;
  const int rr = l & 511;
  const int ho = rr >> 2;
  const int wo0 = (rr & 3) << 5;

  const int tid  = threadIdx.x;
  const int wv   = tid >> 6;
  const int lane = tid & 63;
  const int r    = lane & 15;
  const int g    = lane >> 4;
  const int ob   = (wv & 3) << 5;
  const int pb   = (wv >> 2) << 4;
  const int arow = ob & 32;
  const int cb   = ob & 64;

  // ---- meta: 9 taps x 32 positions, compact 16B/task ----
  if (tid < NTASK) {
    int k = tid >> 5, p = tid & 31;
    int ky = k / 3, kx = k % 3;
    int wo = wo0 + p;
    float dy = off[((b * 18 + 2 * k) * HH + ho) * WW + wo];
    float dx = off[((b * 18 + 2 * k + 1) * HH + ho) * WW + wo];
    float py = dy + (float)(ky + ho - 1);
    float px = dx + (float)(kx + wo - 1);
    float y0f = floorf(py), x0f = floorf(px);
    float ly = py - y0f, lx = px - x0f;
    int y0 = (int)y0f, x0 = (int)x0f;
    int y1 = y0 + 1, x1 = x0 + 1;
    float wy0 = 1.f - ly, wx0 = 1.f - lx;
    bool vy0 = (y0 >= 0) & (y0 < HH), vy1 = (y1 >= 0) & (y1 < HH);
    bool vx0 = (x0 >= 0) & (x0 < WW), vx1 = (x1 >= 0) & (x1 < WW);
    int y0c = imin(imax(y0, 0), HH - 1), y1c = imin(imax(y1, 0), HH - 1);
    int x0c = imin(imax(x0, 0), WW - 1), x1c = imin(imax(x1, 0), WW - 1);
    uint_t i00 = y0c * WW + x0c, i01 = y0c * WW + x1c;
    uint_t i10 = y1c * WW + x0c, i11 = y1c * WW + x1c;
    float f00 = (vy0 && vx0) ? wy0 * wx0 : 0.f;
    float f01 = (vy0 && vx1) ? wy0 * lx  : 0.f;
    float f10 = (vy1 && vx0) ? ly  * wx0 : 0.f;
    float f11 = (vy1 && vx1) ? ly  * lx  : 0.f;
    union { __half h; ushort_t u; } h00, h01, h10, h11;
    h00.h = __float2half_rn(f00); h01.h = __float2half_rn(f01);
    h10.h = __float2half_rn(f10); h11.h = __float2half_rn(f11);
    uint4 m;
    m.x = i00 | (i01 << 16);
    m.y = i10 | (i11 << 16);
    m.z = (uint_t)h00.u | ((uint_t)h01.u << 16);
    m.w = (uint_t)h10.u | ((uint_t)h11.u << 16);
    meta[tid] = m;
  }

  // gather mapping: one task (4 corners, 8 ch) per thread per tap
  const int q  = tid & 15;            // channel octet
  const int p0 = tid >> 4;            // position 0..31
  const char* xb = (const char*)xtb + (size_t)b * NPIX * PIXB + q * 16;

  // A gload mapping: thread copies 16B; pre-swizzled source is linear
  const char* asrc = (const char*)wbf + tid * 16;
  char* adst0 = (char*)Alds + wv * 1024;

  uint4 cf[2][4];     // 2-deep in-flight gather sets (32 VGPR -- needs bound<=4)
  uint2 wr[2];        // corner weights (packed f16) per set

  __syncthreads();  // meta ready (full drain once is fine)

  // ---- prologue ----
  __builtin_amdgcn_sched_barrier(0);
  __builtin_amdgcn_global_load_lds(
      (const __attribute__((address_space(1))) uint_t*)asrc,
      (__attribute__((address_space(3))) uint_t*)adst0, 16, 0, 0);
  __builtin_amdgcn_sched_barrier(0);
  {
    uint4 m = meta[p0];
    cf[0][0] = *(const uint4*)(xb + ((m.x & 0xFFFFu) << 8));
    cf[0][1] = *(const uint4*)(xb + ((m.x >> 16) << 8));
    cf[0][2] = *(const uint4*)(xb + ((m.y & 0xFFFFu) << 8));
    cf[0][3] = *(const uint4*)(xb + ((m.y >> 16) << 8));
    wr[0] = make_uint2(m.z, m.w);
  }
  __builtin_amdgcn_sched_barrier(0);
  {
    uint4 m = meta[32 + p0];
    cf[1][0] = *(const uint4*)(xb + ((m.x & 0xFFFFu) << 8));
    cf[1][1] = *(const uint4*)(xb + ((m.x >> 16) << 8));
    cf[1][2] = *(const uint4*)(xb + ((m.y & 0xFFFFu) << 8));
    cf[1][3] = *(const uint4*)(xb + ((m.y >> 16) << 8));
    wr[1] = make_uint2(m.z, m.w);
  }
  __builtin_amdgcn_sched_barrier(0);
  commit_bilinear(cf[0], wr[0], &Blds[p0 * LDB + q * 8]);   // compiler waits g[0] regs
  asm volatile("s_waitcnt lgkmcnt(0)" ::: "memory");
  asm volatile("s_waitcnt vmcnt(4)" ::: "memory");          // A[0] done; g[1] in flight
  __builtin_amdgcn_sched_barrier(0);
  __builtin_amdgcn_s_barrier();

  f32x4 acc0 = {0.f, 0.f, 0.f, 0.f};
  f32x4 acc1 = {0.f, 0.f, 0.f, 0.f};

  const int o0r = arow + r, o1r = arow + 16 + r;
  const int g0base = (o0r << 3) + g, g0m = o0r & 7;
  const int g1base = (o1r << 3) + g, g1m = o1r & 7;

  // ---- main loop: 9 taps, fully unrolled, 2-deep gather pipeline ----
#pragma unroll
  for (int t = 0; t < 9; ++t) {
    const int bs = t & 1;

    __builtin_amdgcn_sched_barrier(0);
    if (t < 8) {
      __builtin_amdgcn_global_load_lds(
          (const __attribute__((address_space(1))) uint_t*)(asrc + (t + 1) * 8192),
          (__attribute__((address_space(3))) uint_t*)(adst0 + ((t + 1) & 1) * 8192),
          16, 0, 0);
    }
    __builtin_amdgcn_sched_barrier(0);
    if (t < 7) {
      const int n2 = t & 1;            // (t+2)&1
      uint4 m = meta[(t + 2) * 32 + p0];
      cf[n2][0] = *(const uint4*)(xb + ((m.x & 0xFFFFu) << 8));
      cf[n2][1] = *(const uint4*)(xb + ((m.x >> 16) << 8));
      cf[n2][2] = *(const uint4*)(xb + ((m.y & 0xFFFFu) << 8));
      cf[n2][3] = *(const uint4*)(xb + ((m.y >> 16) << 8));
      wr[n2] = make_uint2(m.z, m.w);
    }
    __builtin_amdgcn_sched_barrier(0);

    // GEMM on current buffer: K=64, 2 steps of 32
    {
      const ushort_t* Ab = &Alds[bs * ASZ];
      const ushort_t* Bb = &Blds[bs * BSZ];
#pragma unroll
      for (int ks = 0; ks < 2; ++ks) {
        int kk = ks * 32 + g * 8;
        bf16x8 a0 = *(const bf16x8*)&Ab[(((g0base + (ks << 2)) ^ g0m) << 3)];
        bf16x8 a1 = *(const bf16x8*)&Ab[(((g1base + (ks << 2)) ^ g1m) << 3)];
        bf16x8 bbf = *(const bf16x8*)&Bb[(pb + r) * LDB + cb + kk];
        acc0 = __builtin_amdgcn_mfma_f32_16x16x32_bf16(a0, bbf, acc0, 0, 0, 0);
        acc1 = __builtin_amdgcn_mfma_f32_16x16x32_bf16(a1, bbf, acc1, 0, 0, 0);
      }
    }

    // commit tap t+1 into the other buffer (gathers issued one full phase ago)
    if (t < 8) {
      const int nc = (t + 1) & 1;
      commit_bilinear(cf[nc], wr[nc], &Blds[nc * BSZ + p0 * LDB + q * 8]);
    }

    if (t < 8) {
      asm volatile("s_waitcnt lgkmcnt(0)" ::: "memory");
      if (t < 7) {
        asm volatile("s_waitcnt vmcnt(4)" ::: "memory");  // A[t+1] done; g[t+2] fly
      } else {
        asm volatile("s_waitcnt vmcnt(0)" ::: "memory");  // A[8] done (no gathers)
      }
      __builtin_amdgcn_sched_barrier(0);
      __builtin_amdgcn_s_barrier();
    }
  }

  // ---- epilogue ----
  int wo = wo0 + pb + r;
#pragma unroll
  for (int qq = 0; qq < 4; ++qq) {
    int o0 = ob + 4 * g + qq;
    int o1 = o0 + 16;
    out[((size_t)(b * COUT + o0) * HH + ho) * WW + wo] = acc0[qq] + bias[o0 & 63];
    out[((size_t)(b * COUT + o1) * HH + ho) * WW + wo] = acc1[qq] + bias[o1 & 63];
  }
}

extern "C" void kernel_launch(void* const* d_in, const int* in_sizes, int n_in,
                              void* d_out, int out_size, void* d_ws, size_t ws_size,
                              hipStream_t stream) {
  const float* x      = (const float*)d_in[0];
  const float* offset = (const float*)d_in[1];
  const float* weight = (const float*)d_in[2];
  const float* bias   = (const float*)d_in[3];
  float* out = (float*)d_out;

  const size_t xt_elems = (size_t)4 * NPIX * CIN;           // 8,388,608 bf16
  ushort_t* xtb = (ushort_t*)d_ws;
  ushort_t* wbf = (ushort_t*)((char*)d_ws + xt_elems * sizeof(ushort_t));

  const int off_elems = 4 * 18 * NPIX;
  const int n4 = off_elems / 4;                             // 294912 float4s
  prep_misc<<<144 + (n4 + 255) / 256, 256, 0, stream>>>(
      weight, wbf, (const float4*)offset,
      (float4*)(out + (size_t)4 * COUT * NPIX), n4);

  transpose_nchw_nhwc<<<dim3(512, 4, 4), dim3(32, 8), 0, stream>>>(x, (uint_t*)xtb);

  deform_main<<<2048, 512, 0, stream>>>(xtb, offset, wbf, bias, out);
}

// Round 7
// 46.519 us; speedup vs baseline: 2.5563x; 1.3099x over previous
//
#include <hip/hip_runtime.h>
#include <hip/hip_fp16.h>

typedef unsigned short ushort_t;
typedef unsigned int uint_t;

#define HH 128
#define WW 128
#define CIN 128
#define COUT 128
#define NPIX (HH * WW)          // 16384 pixels per batch
#define PIXB 256                // bytes per f16 pixel (128 ch * 2B)
#define BP 32                   // positions per block
#define LDB 136                 // B row stride elems (128 + 8 pad; 272B = 17*16B)
#define ASZ 4096                // A buffer elems per tap (64 o x 64 c, swizzled)
#define BSZ (BP * LDB)          // 4352
#define NTASK (9 * BP)          // 288

typedef __attribute__((ext_vector_type(8))) _Float16 f16x8;
typedef __attribute__((ext_vector_type(4))) float f32x4;

static __device__ __forceinline__ int imin(int a, int b) { return a < b ? a : b; }
static __device__ __forceinline__ int imax(int a, int b) { return a > b ? a : b; }

static __device__ __forceinline__ ushort_t f2h(float f) {
  union { __half h; ushort_t u; } x; x.h = __float2half(f); return x.u;
}

// packed f16 bilinear: r = w00*c0 + w01*c1 + w10*c2 + w11*c3 (2 channels/uint)
static __device__ __forceinline__ uint_t pk4(uint_t c0, uint_t c1, uint_t c2, uint_t c3,
                                             __half2 w00, __half2 w01,
                                             __half2 w10, __half2 w11) {
  union { uint_t u; __half2 h; } a0, a1, a2, a3, r;
  a0.u = c0; a1.u = c1; a2.u = c2; a3.u = c3;
  r.h = __hfma2(w00, a0.h, __hfma2(w01, a1.h, __hfma2(w10, a2.h, __hmul2(w11, a3.h))));
  return r.u;
}

static __device__ __forceinline__ __half2 dup_lo(uint_t u) {
  union { uint_t u; __half2 h; } x; x.u = (u << 16) | (u & 0xFFFFu); return x.h;
}
static __device__ __forceinline__ __half2 dup_hi(uint_t u) {
  union { uint_t u; __half2 h; } x; x.u = (u >> 16) | (u & 0xFFFF0000u); return x.h;
}

// bilinear commit: 4 corner uint4s (8 f16 ch each) + packed f16 weights -> LDS
static __device__ __forceinline__ void commit_f16(const uint4* cf, uint2 wz, ushort_t* dst) {
  __half2 w00 = dup_lo(wz.x), w01 = dup_hi(wz.x);
  __half2 w10 = dup_lo(wz.y), w11 = dup_hi(wz.y);
  uint4 r;
  r.x = pk4(cf[0].x, cf[1].x, cf[2].x, cf[3].x, w00, w01, w10, w11);
  r.y = pk4(cf[0].y, cf[1].y, cf[2].y, cf[3].y, w00, w01, w10, w11);
  r.z = pk4(cf[0].z, cf[1].z, cf[2].z, cf[3].z, w00, w01, w10, w11);
  r.w = pk4(cf[0].w, cf[1].w, cf[2].w, cf[3].w, w00, w01, w10, w11);
  *(uint4*)dst = r;
}

// K0 (unified prep): blocks [0,8192): transpose BCHW f32 -> NHWC f16;
// [8192,8336): weight -> f16 tap-major XOR-swizzled; [8336,9488): offset copy.
__global__ void prep_all(const float* __restrict__ x, uint_t* __restrict__ xtb,
                         const float* __restrict__ w, ushort_t* __restrict__ wf,
                         const float4* __restrict__ off_in, float4* __restrict__ off_out,
                         int n4) {
  int bid = blockIdx.x;
  int tid = threadIdx.x;
  if (bid < 8192) {
    __shared__ float tile[32][33];
    int b  = bid >> 11;
    int c0 = ((bid >> 9) & 3) * 32;
    int s0 = (bid & 511) * 32;
    int tx = tid & 31;
    int ty = tid >> 5;       // 0..7
    const float* inb = x + (size_t)b * CIN * NPIX;
    uint_t* outb = xtb + (size_t)b * NPIX * (CIN / 2);
#pragma unroll
    for (int i = 0; i < 4; ++i) {
      int c = c0 + ty + 8 * i;
      tile[ty + 8 * i][tx] = inb[(size_t)c * NPIX + s0 + tx];
    }
    __syncthreads();
    int u = tid & 15;        // channel pair
    int sl = tid >> 4;       // 0..15
#pragma unroll
    for (int i = 0; i < 2; ++i) {
      int s = sl + 16 * i;
      __half2 pk = __float22half2_rn(make_float2(tile[2 * u][s], tile[2 * u + 1][s]));
      outb[(size_t)(s0 + s) * (CIN / 2) + (c0 >> 1) + u] = *(uint_t*)&pk;
    }
  } else if (bid < 8192 + 144) {
    // dest elem for (k,o,c): k*4096 + (((o*8 + (c>>3)) ^ (o&7)) * 8 + (c&7))
    int i = (bid - 8192) * 256 + tid;
    int k = i >> 12, e = i & 4095;
    int gp = e >> 3, sub = e & 7;
    int o = gp >> 3;
    int c = (((gp & 7) ^ (o & 7)) << 3) | sub;
    wf[i] = f2h(w[(o * 64 + c) * 9 + k]);
  } else {
    int i = (bid - 8336) * 256 + tid;
    if (i < n4) off_out[i] = off_in[i];
  }
}

// K1: fused gather + MFMA. 2048 blocks x 512 thr. Tile: 128 o x 32 pos, 9 taps.
__global__ __launch_bounds__(512, 4)
void deform_main(const ushort_t* __restrict__ xtb, const float* __restrict__ off,
                 const ushort_t* __restrict__ wf, const float* __restrict__ bias,
                 float* __restrict__ out) {
  __shared__ __align__(16) ushort_t Alds[2 * ASZ];   // weight f16, swizzled granules
  __shared__ __align__(16) ushort_t Blds[2 * BSZ];   // val f16 [p][c]
  __shared__ __align__(16) int4  mo[NTASK];          // 4 corner byte offsets
  __shared__ __align__(16) uint2 mw[NTASK];          // 4 packed f16 weights

  const int n  = blockIdx.x;
  const int l  = (n & 7) * 256 + (n >> 3);           // XCD swizzle (2048%8==0)
  const int b  = l >> 9;
  const int rr = l & 511;
  const int ho = rr >> 2;
  const int wo0 = (rr & 3) << 5;

  const int tid  = threadIdx.x;
  const int wv   = tid >> 6;
  const int lane = tid & 63;
  const int r    = lane & 15;
  const int g    = lane >> 4;
  const int ob   = (wv & 3) << 5;
  const int pb   = (wv >> 2) << 4;
  const int arow = ob & 32;
  const int cb   = ob & 64;

  // ---- meta: 9 taps x 32 positions ----
  if (tid < NTASK) {
    int k = tid >> 5, p = tid & 31;
    int ky = k / 3, kx = k % 3;
    int wo = wo0 + p;
    float dy = off[((b * 18 + 2 * k) * HH + ho) * WW + wo];
    float dx = off[((b * 18 + 2 * k + 1) * HH + ho) * WW + wo];
    float py = dy + (float)(ky + ho - 1);
    float px = dx + (float)(kx + wo - 1);
    float y0f = floorf(py), x0f = floorf(px);
    float ly = py - y0f, lx = px - x0f;
    int y0 = (int)y0f, x0 = (int)x0f;
    int y1 = y0 + 1, x1 = x0 + 1;
    float wy0 = 1.f - ly, wx0 = 1.f - lx;
    bool vy0 = (y0 >= 0) & (y0 < HH), vy1 = (y1 >= 0) & (y1 < HH);
    bool vx0 = (x0 >= 0) & (x0 < WW), vx1 = (x1 >= 0) & (x1 < WW);
    int y0c = imin(imax(y0, 0), HH - 1), y1c = imin(imax(y1, 0), HH - 1);
    int x0c = imin(imax(x0, 0), WW - 1), x1c = imin(imax(x1, 0), WW - 1);
    float f00 = (vy0 && vx0) ? wy0 * wx0 : 0.f;
    float f01 = (vy0 && vx1) ? wy0 * lx  : 0.f;
    float f10 = (vy1 && vx0) ? ly  * wx0 : 0.f;
    float f11 = (vy1 && vx1) ? ly  * lx  : 0.f;
    int4 o4;
    o4.x = (y0c * WW + x0c) * PIXB;
    o4.y = (y0c * WW + x1c) * PIXB;
    o4.z = (y1c * WW + x0c) * PIXB;
    o4.w = (y1c * WW + x1c) * PIXB;
    mo[tid] = o4;
    mw[tid] = make_uint2((uint_t)f2h(f00) | ((uint_t)f2h(f01) << 16),
                         (uint_t)f2h(f10) | ((uint_t)f2h(f11) << 16));
  }

  // gather mapping: one task (4 corners, 8 ch) per thread per tap
  const int q  = tid & 15;            // channel octet
  const int p0 = tid >> 4;            // position 0..31
  const char* xq = (const char*)xtb + (size_t)b * NPIX * PIXB + q * 16;

  // A gload mapping: thread copies 16B; pre-swizzled source is linear
  const char* asrc = (const char*)wf + tid * 16;
  char* adst0 = (char*)Alds + wv * 1024;

  uint4 cf[4];      // in-flight gather (one task)
  uint2 wz;

  __syncthreads();  // meta ready

  // ---- prologue: tap 0 into buffer 0 ----
  {
    __builtin_amdgcn_global_load_lds(
        (const __attribute__((address_space(1))) uint_t*)asrc,
        (__attribute__((address_space(3))) uint_t*)adst0, 16, 0, 0);
    int4 o4 = mo[p0];
    wz = mw[p0];
    cf[0] = *(const uint4*)(xq + o4.x);
    cf[1] = *(const uint4*)(xq + o4.y);
    cf[2] = *(const uint4*)(xq + o4.z);
    cf[3] = *(const uint4*)(xq + o4.w);
    commit_f16(cf, wz, &Blds[p0 * LDB + q * 8]);
  }
  __syncthreads();

  f32x4 acc0 = {0.f, 0.f, 0.f, 0.f};
  f32x4 acc1 = {0.f, 0.f, 0.f, 0.f};

  const int o0r = arow + r, o1r = arow + 16 + r;
  const int g0base = (o0r << 3) + g, g0m = o0r & 7;
  const int g1base = (o1r << 3) + g, g1m = o1r & 7;

  // ---- main loop: 9 taps, double-buffered, 1-tap lookahead ----
  for (int t = 0; t < 9; ++t) {
    const int bs = t & 1, ns = bs ^ 1;

    if (t < 8) {
      __builtin_amdgcn_global_load_lds(
          (const __attribute__((address_space(1))) uint_t*)(asrc + (t + 1) * 8192),
          (__attribute__((address_space(3))) uint_t*)(adst0 + ns * 8192), 16, 0, 0);
      int4 o4 = mo[(t + 1) * 32 + p0];
      wz = mw[(t + 1) * 32 + p0];
      cf[0] = *(const uint4*)(xq + o4.x);
      cf[1] = *(const uint4*)(xq + o4.y);
      cf[2] = *(const uint4*)(xq + o4.z);
      cf[3] = *(const uint4*)(xq + o4.w);
    }
    __builtin_amdgcn_sched_barrier(0);   // keep issue-block above GEMM (no sinking)

    // GEMM on current buffer: K=64, 2 steps of 32
    {
      const ushort_t* Ab = &Alds[bs * ASZ];
      const ushort_t* Bb = &Blds[bs * BSZ];
#pragma unroll
      for (int ks = 0; ks < 2; ++ks) {
        int kk = ks * 32 + g * 8;
        f16x8 a0 = *(const f16x8*)&Ab[(((g0base + (ks << 2)) ^ g0m) << 3)];
        f16x8 a1 = *(const f16x8*)&Ab[(((g1base + (ks << 2)) ^ g1m) << 3)];
        f16x8 bbf = *(const f16x8*)&Bb[(pb + r) * LDB + cb + kk];
        acc0 = __builtin_amdgcn_mfma_f32_16x16x32_f16(a0, bbf, acc0, 0, 0, 0);
        acc1 = __builtin_amdgcn_mfma_f32_16x16x32_f16(a1, bbf, acc1, 0, 0, 0);
      }
    }

    // commit tap t+1 into the other buffer
    if (t < 8) {
      commit_f16(cf, wz, &Blds[ns * BSZ + p0 * LDB + q * 8]);
    }
    __syncthreads();
  }

  // ---- epilogue: D col = lane&15 (pos), row = 4*(lane>>4)+reg (o) ----
  int wo = wo0 + pb + r;
#pragma unroll
  for (int qq = 0; qq < 4; ++qq) {
    int o0 = ob + 4 * g + qq;
    int o1 = o0 + 16;
    out[((size_t)(b * COUT + o0) * HH + ho) * WW + wo] = acc0[qq] + bias[o0 & 63];
    out[((size_t)(b * COUT + o1) * HH + ho) * WW + wo] = acc1[qq] + bias[o1 & 63];
  }
}

extern "C" void kernel_launch(void* const* d_in, const int* in_sizes, int n_in,
                              void* d_out, int out_size, void* d_ws, size_t ws_size,
                              hipStream_t stream) {
  const float* x      = (const float*)d_in[0];
  const float* offset = (const float*)d_in[1];
  const float* weight = (const float*)d_in[2];
  const float* bias   = (const float*)d_in[3];
  float* out = (float*)d_out;

  const size_t xt_elems = (size_t)4 * NPIX * CIN;           // 8,388,608 f16
  ushort_t* xtb = (ushort_t*)d_ws;
  ushort_t* wf  = (ushort_t*)((char*)d_ws + xt_elems * sizeof(ushort_t));

  const int off_elems = 4 * 18 * NPIX;
  const int n4 = off_elems / 4;                             // 294912 float4s

  prep_all<<<8192 + 144 + 1152, 256, 0, stream>>>(
      x, (uint_t*)xtb, weight, wf, (const float4*)offset,
      (float4*)(out + (size_t)4 * COUT * NPIX), n4);

  deform_main<<<2048, 512, 0, stream>>>(xtb, offset, wf, bias, out);
}